// Round 7
// baseline (424.857 us; speedup 1.0000x reference)
//
#include <hip/hip_runtime.h>
#include <cstdint>
#include <cstddef>

#define NN 50000      // nodes
#define NE 800000     // edges
#define DF 128        // feature dim
#define HF 256        // hidden dim
#define NR 4          // dropout runs

typedef __attribute__((ext_vector_type(8))) short short8;   // 8 bf16 = 4 VGPR
typedef __attribute__((ext_vector_type(4))) float f32x4;    // MFMA C/D

// ws layout: W1T [256][128] bf16 | W2T [128][256] bf16 | deg | rowstart | cursor | adj | flag | bits
static const size_t W1T_OFF = 0;
static const size_t W2T_OFF = (size_t)DF * HF;              // in bf16 elems
static const size_t INT_OFF = W2T_OFF + (size_t)DF * HF;    // bf16 elems before int region

__device__ __forceinline__ unsigned short f2bf(float f) {   // RNE fp32->bf16
  union { float f; unsigned u; } v; v.f = f;
  unsigned r = v.u + 0x7FFF + ((v.u >> 16) & 1);
  return (unsigned short)(r >> 16);
}

// packed 2xbf16 convert: dst.lo = bf16(a), dst.hi = bf16(b)   (T12 recipe)
__device__ __forceinline__ unsigned cvtpk(float a, float b) {
  unsigned r;
  asm("v_cvt_pk_bf16_f32 %0, %1, %2" : "=v"(r) : "v"(a), "v"(b));
  return r;
}

// mish(z) = z*tanh(softplus(z)) = z - 2z/((1+e^z)^2+1); branch-free:
// z>>0: t=inf -> rcp=0 -> z.  z<<0: t=0 -> z-2z*0.5 = 0.
__device__ __forceinline__ float mishf(float z) {
  float t = __expf(z);
  float u = fmaf(t, t + 2.f, 1.f);          // (1+t)^2
  float r = __builtin_amdgcn_rcpf(u + 1.f);
  return fmaf(-(z + z), r, z);
}

// init: zero deg, zero dtype flag, build bf16 transposed weights
__global__ __launch_bounds__(256) void k_init(const float* __restrict__ W1,
    const float* __restrict__ W2, unsigned short* __restrict__ W1T,
    unsigned short* __restrict__ W2T, int* __restrict__ deg, int* __restrict__ flag) {
  int i = blockIdx.x * 256 + threadIdx.x;     // 65536 threads
  if (i < NN) deg[i] = 0;
  if (i == 0) *flag = 0;
  if (i < DF * HF) {
    int n = i >> 7, k = i & 127;              // W1T[n][k] = W1[k][n]
    W1T[i] = f2bf(W1[(size_t)k * HF + n]);
    int n2 = i >> 8, k2 = i & 255;            // W2T[n2][k2] = W2[k2][n2]
    W2T[i] = f2bf(W2[(size_t)k2 * DF + n2]);
  }
}

// drop_mask dtype detect: int32 {0,1} -> bytes at i%4!=0 all zero; byte-bool -> many nonzero
__global__ __launch_bounds__(256) void k_detect(const unsigned char* __restrict__ dropb,
                                                int* __restrict__ flag) {
  int i = blockIdx.x * 256 + threadIdx.x;
  if (i < NR * NN && (i & 3) != 0 && dropb[i] != 0) atomicOr(flag, 1);
}

// fused: per-edge degree histogram + per-node drop-bit pack
__global__ __launch_bounds__(256) void k_packhist(const unsigned char* __restrict__ dropb,
    const int* __restrict__ dropi, const int* __restrict__ flag,
    unsigned char* __restrict__ bits, const int* __restrict__ ei, int* __restrict__ deg) {
  int t = blockIdx.x * 256 + threadIdx.x;
  if (t < NE) atomicAdd(&deg[ei[NE + t]], 1);
  if (t < NN) {
    const int byte_mode = *flag;
    unsigned b = 0;
#pragma unroll
    for (int r = 0; r < NR; ++r) {
      int v = byte_mode ? (int)dropb[(size_t)r * NN + t] : dropi[(size_t)r * NN + t];
      b |= (v != 0 ? 1u : 0u) << r;
    }
    bits[t] = (unsigned char)b;
  }
}

// single-block exclusive scan of deg -> rowstart, cursor
__global__ __launch_bounds__(1024) void k_scan(const int* __restrict__ deg,
    int* __restrict__ rowstart, int* __restrict__ cursor) {
  __shared__ int s[1024];
  const int t = threadIdx.x;
  const int lo = t * 49, hi = (lo + 49 < NN) ? lo + 49 : NN;
  int loc = 0;
  for (int j = lo; j < hi; ++j) loc += deg[j];
  s[t] = loc; __syncthreads();
  for (int off = 1; off < 1024; off <<= 1) {
    int a = s[t]; int b = (t >= off) ? s[t - off] : 0;
    __syncthreads(); s[t] = a + b; __syncthreads();
  }
  int run = s[t] - loc;
  for (int j = lo; j < hi; ++j) { rowstart[j] = run; cursor[j] = run; run += deg[j]; }
}

__global__ __launch_bounds__(256) void k_fill(const int* __restrict__ ei,
    int* __restrict__ cursor, int* __restrict__ adj) {
  int e = blockIdx.x * 256 + threadIdx.x;
  if (e < NE) {
    int src = ei[e], dst = ei[NE + e];
    int pos = atomicAdd(&cursor[dst], 1);
    adj[pos] = src;
  }
}

// Fused gather + MLP. Block = 16 nodes (64 rows = node x 4 runs), 256 threads.
// Phase G: CSR gather (16 lanes/node, 8 dims/lane) -> H rows as bf16 in swizzled LDS.
// Phase 1: GEMM1 SWAPPED mfma(W1frag, Hfrag) -> D[hidden][row]: thread holds 4
//          consecutive hidden cols -> float4 bias + mish + cvt_pk -> one b64 As write.
// Phase 2: GEMM2 mfma(Asfrag, W2Tfrag) -> D[row][out]: thread's 4 regs = 4 runs of
//          one node -> in-register run-mean + bias + residual.
__global__ __launch_bounds__(256) void k_mlp(const float* __restrict__ x,
    const int* __restrict__ adj, const int* __restrict__ rowstart,
    const int* __restrict__ deg, const unsigned char* __restrict__ bits,
    const unsigned short* __restrict__ W1T, const unsigned short* __restrict__ W2T,
    const float* __restrict__ b1, const float* __restrict__ b2,
    float* __restrict__ out) {
  __shared__ __align__(16) unsigned char lds[49152];
  unsigned char* HsB = lds;            // [64 rows][256 B] bf16, 16B-chunk XOR swizzle
  unsigned char* AsB = lds + 16384;    // [64 rows][512 B] bf16, same swizzle

  const int tid = threadIdx.x;

  // ---------------- Phase G: gather ----------------
  {
    const int ln = tid >> 4, li = tid & 15;          // node-local, lane-in-node
    const int n = blockIdx.x * 16 + ln;
    const int d0 = li * 8;
    const int start = rowstart[n], dg = deg[n];
    float s[8] = {0, 0, 0, 0, 0, 0, 0, 0};
    float c[NR][8] = {};

    int i = 0;
    for (; i + 2 <= dg; i += 2) {
      int s0 = adj[start + i], s1 = adj[start + i + 1];
      const float4 a0 = *(const float4*)&x[(size_t)s0 * DF + d0];
      const float4 a1 = *(const float4*)&x[(size_t)s0 * DF + d0 + 4];
      const float4 b0 = *(const float4*)&x[(size_t)s1 * DF + d0];
      const float4 b1v = *(const float4*)&x[(size_t)s1 * DF + d0 + 4];
      unsigned m0 = bits[s0], m1 = bits[s1];
      s[0] += a0.x + b0.x; s[1] += a0.y + b0.y; s[2] += a0.z + b0.z; s[3] += a0.w + b0.w;
      s[4] += a1.x + b1v.x; s[5] += a1.y + b1v.y; s[6] += a1.z + b1v.z; s[7] += a1.w + b1v.w;
#pragma unroll
      for (int r = 0; r < NR; ++r) {
        if ((m0 >> r) & 1) {
          c[r][0] += a0.x; c[r][1] += a0.y; c[r][2] += a0.z; c[r][3] += a0.w;
          c[r][4] += a1.x; c[r][5] += a1.y; c[r][6] += a1.z; c[r][7] += a1.w;
        }
        if ((m1 >> r) & 1) {
          c[r][0] += b0.x; c[r][1] += b0.y; c[r][2] += b0.z; c[r][3] += b0.w;
          c[r][4] += b1v.x; c[r][5] += b1v.y; c[r][6] += b1v.z; c[r][7] += b1v.w;
        }
      }
    }
    if (i < dg) {
      int s0 = adj[start + i];
      const float4 a0 = *(const float4*)&x[(size_t)s0 * DF + d0];
      const float4 a1 = *(const float4*)&x[(size_t)s0 * DF + d0 + 4];
      unsigned m0 = bits[s0];
      s[0] += a0.x; s[1] += a0.y; s[2] += a0.z; s[3] += a0.w;
      s[4] += a1.x; s[5] += a1.y; s[6] += a1.z; s[7] += a1.w;
#pragma unroll
      for (int r = 0; r < NR; ++r)
        if ((m0 >> r) & 1) {
          c[r][0] += a0.x; c[r][1] += a0.y; c[r][2] += a0.z; c[r][3] += a0.w;
          c[r][4] += a1.x; c[r][5] += a1.y; c[r][6] += a1.z; c[r][7] += a1.w;
        }
    }

    const float4 x0 = *(const float4*)&x[(size_t)n * DF + d0];
    const float4 x1 = *(const float4*)&x[(size_t)n * DF + d0 + 4];
    const float xs[8] = {x0.x, x0.y, x0.z, x0.w, x1.x, x1.y, x1.z, x1.w};
    const unsigned bn = bits[n];
#pragma unroll
    for (int r = 0; r < NR; ++r) {
      float h[8];
      const float keep = ((bn >> r) & 1) ? 0.f : 1.f;
#pragma unroll
      for (int j = 0; j < 8; ++j) h[j] = s[j] - c[r][j] + keep * xs[j];
      uint4 p;
      p.x = cvtpk(h[0], h[1]); p.y = cvtpk(h[2], h[3]);
      p.z = cvtpk(h[4], h[5]); p.w = cvtpk(h[6], h[7]);
      const int row = ln * 4 + r;
      *(uint4*)(HsB + row * 256 + ((li * 16) ^ ((row & 7) << 4))) = p;
    }
  }
  __syncthreads();

  // ---------------- Phase 1: GEMM1 (swapped) ----------------
  const int wid = tid >> 6, lane = tid & 63;
  const int lg = lane >> 4, lr = lane & 15;
  const int swz = (lr & 7) << 4;

  f32x4 acc1[4][4] = {};   // [ht][rt]: D[hidden = wid*64+ht*16+lg*4+i][row = rt*16+lr]
#pragma unroll
  for (int ks = 0; ks < 4; ++ks) {
    short8 Bf[4];
#pragma unroll
    for (int rt = 0; rt < 4; ++rt)
      Bf[rt] = *(const short8*)(HsB + (rt * 16 + lr) * 256 + ((ks * 64 + lg * 16) ^ swz));
#pragma unroll
    for (int ht = 0; ht < 4; ++ht) {
      short8 Af = *(const short8*)(W1T + (size_t)(wid * 64 + ht * 16 + lr) * DF + ks * 32 + lg * 8);
#pragma unroll
      for (int rt = 0; rt < 4; ++rt)
        acc1[ht][rt] = __builtin_amdgcn_mfma_f32_16x16x32_bf16(Af, Bf[rt], acc1[ht][rt], 0, 0, 0);
    }
  }

  // bias + mish + packed As write (one b64 per (ht,rt))
#pragma unroll
  for (int ht = 0; ht < 4; ++ht) {
    const float4 bb = *(const float4*)&b1[wid * 64 + ht * 16 + lg * 4];
    const int chunk = wid * 128 + ht * 32 + (lg >> 1) * 16;
    const int sub = (lg & 1) * 8;
#pragma unroll
    for (int rt = 0; rt < 4; ++rt) {
      const int row = rt * 16 + lr;
      float m0 = mishf(acc1[ht][rt][0] + bb.x);
      float m1 = mishf(acc1[ht][rt][1] + bb.y);
      float m2 = mishf(acc1[ht][rt][2] + bb.z);
      float m3 = mishf(acc1[ht][rt][3] + bb.w);
      uint2 p; p.x = cvtpk(m0, m1); p.y = cvtpk(m2, m3);
      *(uint2*)(AsB + row * 512 + (chunk ^ ((row & 7) << 4)) + sub) = p;
    }
  }
  __syncthreads();

  // ---------------- Phase 2: GEMM2 ----------------
  f32x4 acc2[4][2] = {};   // [m][nr]: D[row = m*16+lg*4+reg][col = wid*32+nr*16+lr]
#pragma unroll
  for (int ks = 0; ks < 8; ++ks) {
    short8 Af[4];
#pragma unroll
    for (int m = 0; m < 4; ++m)
      Af[m] = *(const short8*)(AsB + (m * 16 + lr) * 512 + ((ks * 64 + lg * 16) ^ swz));
#pragma unroll
    for (int nr = 0; nr < 2; ++nr) {
      short8 Bf = *(const short8*)(W2T + (size_t)(wid * 32 + nr * 16 + lr) * HF + ks * 32 + lg * 8);
#pragma unroll
      for (int m = 0; m < 4; ++m)
        acc2[m][nr] = __builtin_amdgcn_mfma_f32_16x16x32_bf16(Af[m], Bf, acc2[m][nr], 0, 0, 0);
    }
  }

  // run-mean + bias + residual
  const int nodebase = blockIdx.x * 16;
#pragma unroll
  for (int m = 0; m < 4; ++m) {
    const int node = nodebase + m * 4 + lg;
#pragma unroll
    for (int nr = 0; nr < 2; ++nr) {
      const int col = wid * 32 + nr * 16 + lr;
      float mean = 0.25f * (acc2[m][nr][0] + acc2[m][nr][1] + acc2[m][nr][2] + acc2[m][nr][3]);
      out[(size_t)node * DF + col] = mean + b2[col] + x[(size_t)node * DF + col];
    }
  }
}

extern "C" void kernel_launch(void* const* d_in, const int* in_sizes, int n_in,
                              void* d_out, int out_size, void* d_ws, size_t ws_size,
                              hipStream_t stream) {
  const float* x             = (const float*)d_in[0];
  const int* ei              = (const int*)d_in[1];
  const unsigned char* dropb = (const unsigned char*)d_in[2];
  const int* dropi           = (const int*)d_in[2];
  const float* W1            = (const float*)d_in[3];
  const float* b1            = (const float*)d_in[4];
  const float* W2            = (const float*)d_in[5];
  const float* b2            = (const float*)d_in[6];
  float* out = (float*)d_out;

  unsigned short* wsh = (unsigned short*)d_ws;
  unsigned short* W1T = wsh + W1T_OFF;
  unsigned short* W2T = wsh + W2T_OFF;
  int* deg      = (int*)(wsh + INT_OFF);
  int* rowstart = deg + NN;
  int* cursor   = rowstart + NN;
  int* adj      = cursor + NN;
  int* flag     = adj + NE;
  unsigned char* bits = (unsigned char*)(flag + 1);

  k_init<<<256, 256, 0, stream>>>(W1, W2, W1T, W2T, deg, flag);
  k_detect<<<(NR * NN + 255) / 256, 256, 0, stream>>>(dropb, flag);
  k_packhist<<<(NE + 255) / 256, 256, 0, stream>>>(dropb, dropi, flag, bits, ei, deg);
  k_scan<<<1, 1024, 0, stream>>>(deg, rowstart, cursor);
  k_fill<<<(NE + 255) / 256, 256, 0, stream>>>(ei, cursor, adj);
  k_mlp<<<NN / 16, 256, 0, stream>>>(x, adj, rowstart, deg, bits, W1T, W2T, b1, b2, out);
}

// Round 13
// 285.840 us; speedup vs baseline: 1.4863x; 1.4863x over previous
//
#include <hip/hip_runtime.h>
#include <cstdint>
#include <cstddef>

#define NN 50000      // nodes
#define NE 800000     // edges
#define DF 128        // feature dim
#define HF 256        // hidden dim
#define NR 4          // dropout runs
#define NB1 196       // ceil(NN/256)

typedef __attribute__((ext_vector_type(8))) short short8;   // 8 bf16 = 4 VGPR
typedef __attribute__((ext_vector_type(4))) float f32x4;    // MFMA C/D

// ws layout (bf16 elems): W1T [256][128] | W2T [128][256] | xbf [NN][DF] | ints...
static const size_t W1T_OFF = 0;
static const size_t W2T_OFF = (size_t)DF * HF;
static const size_t XBF_OFF = W2T_OFF + (size_t)DF * HF;
static const size_t INT_OFF = XBF_OFF + (size_t)NN * DF;    // bf16 elems before int region

__device__ __forceinline__ unsigned short f2bf(float f) {   // RNE fp32->bf16
  union { float f; unsigned u; } v; v.f = f;
  unsigned r = v.u + 0x7FFF + ((v.u >> 16) & 1);
  return (unsigned short)(r >> 16);
}

// packed 2xbf16 convert: dst.lo = bf16(a), dst.hi = bf16(b)
__device__ __forceinline__ unsigned cvtpk(float a, float b) {
  unsigned r;
  asm("v_cvt_pk_bf16_f32 %0, %1, %2" : "=v"(r) : "v"(a), "v"(b));
  return r;
}

// mish(z) = z - 2z/((1+e^z)^2+1); branch-free (z>>0: rcp->0 -> z; z<<0: -> 0)
__device__ __forceinline__ float mishf(float z) {
  float t = __expf(z);
  float u = fmaf(t, t + 2.f, 1.f);
  float r = __builtin_amdgcn_rcpf(u + 1.f);
  return fmaf(-(z + z), r, z);
}

// init: zero deg + flag, bf16 transposed weights, bf16 copy of x
__global__ __launch_bounds__(256) void k_init(const float* __restrict__ W1,
    const float* __restrict__ W2, const float* __restrict__ x,
    unsigned short* __restrict__ W1T, unsigned short* __restrict__ W2T,
    unsigned short* __restrict__ xbf, int* __restrict__ deg, int* __restrict__ flag) {
  int i = blockIdx.x * 256 + threadIdx.x;     // grid 6250*256 = 1.6M
  if (i < NN) deg[i] = 0;
  if (i == 0) *flag = 0;
  if (i < DF * HF) {
    int n = i >> 7, k = i & 127;              // W1T[n][k] = W1[k][n]
    W1T[i] = f2bf(W1[(size_t)k * HF + n]);
    int n2 = i >> 8, k2 = i & 255;            // W2T[n2][k2] = W2[k2][n2]
    W2T[i] = f2bf(W2[(size_t)k2 * DF + n2]);
  }
  {                                           // xbf: 4 floats per thread
    const float4 v = *(const float4*)&x[(size_t)i * 4];
    uint2 p; p.x = cvtpk(v.x, v.y); p.y = cvtpk(v.z, v.w);
    *(uint2*)&xbf[(size_t)i * 4] = p;
  }
}

// drop_mask dtype detect: int32 {0,1} -> bytes at i%4!=0 all zero; byte-bool -> many nonzero
__global__ __launch_bounds__(256) void k_detect(const unsigned char* __restrict__ dropb,
                                                int* __restrict__ flag) {
  int i = blockIdx.x * 256 + threadIdx.x;
  if (i < NR * NN && (i & 3) != 0 && dropb[i] != 0) atomicOr(flag, 1);
}

// fused: per-edge degree histogram + per-node drop-bit pack
__global__ __launch_bounds__(256) void k_packhist(const unsigned char* __restrict__ dropb,
    const int* __restrict__ dropi, const int* __restrict__ flag,
    unsigned char* __restrict__ bits, const int* __restrict__ ei, int* __restrict__ deg) {
  int t = blockIdx.x * 256 + threadIdx.x;
  if (t < NE) atomicAdd(&deg[ei[NE + t]], 1);
  if (t < NN) {
    const int byte_mode = *flag;
    unsigned b = 0;
#pragma unroll
    for (int r = 0; r < NR; ++r) {
      int v = byte_mode ? (int)dropb[(size_t)r * NN + t] : dropi[(size_t)r * NN + t];
      b |= (v != 0 ? 1u : 0u) << r;
    }
    bits[t] = (unsigned char)b;
  }
}

// multi-block exclusive scan (3 kernels — parallel; the single-block scan was a ~150us serialization)
__global__ __launch_bounds__(256) void k_scan1(const int* __restrict__ deg,
    int* __restrict__ rowstart, int* __restrict__ bsum) {
  __shared__ int s[256];
  int t = threadIdx.x, n = blockIdx.x * 256 + t;
  int v = (n < NN) ? deg[n] : 0;
  s[t] = v; __syncthreads();
  for (int off = 1; off < 256; off <<= 1) {
    int a = s[t]; int b = (t >= off) ? s[t - off] : 0;
    __syncthreads(); s[t] = a + b; __syncthreads();
  }
  if (n < NN) rowstart[n] = s[t] - v;
  if (t == 255) bsum[blockIdx.x] = s[255];
}

__global__ __launch_bounds__(256) void k_scan2(const int* __restrict__ bsum, int* __restrict__ boff) {
  __shared__ int s[256];
  int t = threadIdx.x;
  int v = (t < NB1) ? bsum[t] : 0;
  s[t] = v; __syncthreads();
  for (int off = 1; off < 256; off <<= 1) {
    int a = s[t]; int b = (t >= off) ? s[t - off] : 0;
    __syncthreads(); s[t] = a + b; __syncthreads();
  }
  if (t < NB1) boff[t] = s[t] - v;
}

__global__ __launch_bounds__(256) void k_scan3(int* __restrict__ rowstart,
    const int* __restrict__ boff, int* __restrict__ cursor) {
  int n = blockIdx.x * 256 + threadIdx.x;
  if (n < NN) {
    int rs = rowstart[n] + boff[blockIdx.x];
    rowstart[n] = rs;
    cursor[n] = rs;
  }
}

// fill CSR; adj entry = src | (drop_bits(src) << 16)   (src < 2^16)
__global__ __launch_bounds__(256) void k_fill(const int* __restrict__ ei,
    const unsigned char* __restrict__ bits, int* __restrict__ cursor,
    unsigned* __restrict__ adj) {
  int e = blockIdx.x * 256 + threadIdx.x;
  if (e < NE) {
    int src = ei[e], dst = ei[NE + e];
    int pos = atomicAdd(&cursor[dst], 1);
    adj[pos] = (unsigned)src | ((unsigned)bits[src] << 16);
  }
}

// Fused gather + MLP. Block = 16 nodes (64 rows = node x 4 runs), 256 threads.
// Phase G: CSR gather from bf16 x (16 lanes/node, 8 dims/lane) -> swizzled LDS.
// Phase 1: GEMM1 swapped mfma(W1frag,Hfrag) -> D[hidden][row]; bias+mish+cvt_pk -> As.
// Phase 2: GEMM2 mfma(Asfrag,W2Tfrag) -> D[row][out]; in-register run-mean+bias+residual.
__global__ __launch_bounds__(256) void k_mlp(const float* __restrict__ x,
    const unsigned short* __restrict__ xbf,
    const unsigned* __restrict__ adj, const int* __restrict__ rowstart,
    const int* __restrict__ deg, const unsigned char* __restrict__ bits,
    const unsigned short* __restrict__ W1T, const unsigned short* __restrict__ W2T,
    const float* __restrict__ b1, const float* __restrict__ b2,
    float* __restrict__ out) {
  __shared__ __align__(16) unsigned char lds[49152];
  unsigned char* HsB = lds;            // [64 rows][256 B] bf16, 16B-chunk XOR swizzle
  unsigned char* AsB = lds + 16384;    // [64 rows][512 B] bf16, same swizzle

  const int tid = threadIdx.x;

  // ---------------- Phase G: gather (bf16 src rows) ----------------
  {
    const int ln = tid >> 4, li = tid & 15;
    const int n = blockIdx.x * 16 + ln;
    const int d0 = li * 8;
    const int start = rowstart[n], dg = deg[n];
    float s[8] = {0, 0, 0, 0, 0, 0, 0, 0};
    float c[NR][8] = {};

    int i = 0;
    for (; i + 2 <= dg; i += 2) {
      unsigned e0 = adj[start + i], e1 = adj[start + i + 1];
      const uint4 q0 = *(const uint4*)&xbf[(size_t)(e0 & 0xFFFF) * DF + d0];
      const uint4 q1 = *(const uint4*)&xbf[(size_t)(e1 & 0xFFFF) * DF + d0];
      const unsigned m0 = e0 >> 16, m1 = e1 >> 16;
      float v0[8], v1[8];
      v0[0] = __uint_as_float(q0.x << 16); v0[1] = __uint_as_float(q0.x & 0xFFFF0000u);
      v0[2] = __uint_as_float(q0.y << 16); v0[3] = __uint_as_float(q0.y & 0xFFFF0000u);
      v0[4] = __uint_as_float(q0.z << 16); v0[5] = __uint_as_float(q0.z & 0xFFFF0000u);
      v0[6] = __uint_as_float(q0.w << 16); v0[7] = __uint_as_float(q0.w & 0xFFFF0000u);
      v1[0] = __uint_as_float(q1.x << 16); v1[1] = __uint_as_float(q1.x & 0xFFFF0000u);
      v1[2] = __uint_as_float(q1.y << 16); v1[3] = __uint_as_float(q1.y & 0xFFFF0000u);
      v1[4] = __uint_as_float(q1.z << 16); v1[5] = __uint_as_float(q1.z & 0xFFFF0000u);
      v1[6] = __uint_as_float(q1.w << 16); v1[7] = __uint_as_float(q1.w & 0xFFFF0000u);
#pragma unroll
      for (int j = 0; j < 8; ++j) s[j] += v0[j] + v1[j];
#pragma unroll
      for (int r = 0; r < NR; ++r) {
        if ((m0 >> r) & 1) {
#pragma unroll
          for (int j = 0; j < 8; ++j) c[r][j] += v0[j];
        }
        if ((m1 >> r) & 1) {
#pragma unroll
          for (int j = 0; j < 8; ++j) c[r][j] += v1[j];
        }
      }
    }
    if (i < dg) {
      unsigned e0 = adj[start + i];
      const uint4 q0 = *(const uint4*)&xbf[(size_t)(e0 & 0xFFFF) * DF + d0];
      const unsigned m0 = e0 >> 16;
      float v0[8];
      v0[0] = __uint_as_float(q0.x << 16); v0[1] = __uint_as_float(q0.x & 0xFFFF0000u);
      v0[2] = __uint_as_float(q0.y << 16); v0[3] = __uint_as_float(q0.y & 0xFFFF0000u);
      v0[4] = __uint_as_float(q0.z << 16); v0[5] = __uint_as_float(q0.z & 0xFFFF0000u);
      v0[6] = __uint_as_float(q0.w << 16); v0[7] = __uint_as_float(q0.w & 0xFFFF0000u);
#pragma unroll
      for (int j = 0; j < 8; ++j) s[j] += v0[j];
#pragma unroll
      for (int r = 0; r < NR; ++r)
        if ((m0 >> r) & 1) {
#pragma unroll
          for (int j = 0; j < 8; ++j) c[r][j] += v0[j];
        }
    }

    const float4 x0 = *(const float4*)&x[(size_t)n * DF + d0];
    const float4 x1 = *(const float4*)&x[(size_t)n * DF + d0 + 4];
    const float xs[8] = {x0.x, x0.y, x0.z, x0.w, x1.x, x1.y, x1.z, x1.w};
    const unsigned bn = bits[n];
#pragma unroll
    for (int r = 0; r < NR; ++r) {
      float h[8];
      const float keep = ((bn >> r) & 1) ? 0.f : 1.f;
#pragma unroll
      for (int j = 0; j < 8; ++j) h[j] = s[j] - c[r][j] + keep * xs[j];
      uint4 p;
      p.x = cvtpk(h[0], h[1]); p.y = cvtpk(h[2], h[3]);
      p.z = cvtpk(h[4], h[5]); p.w = cvtpk(h[6], h[7]);
      const int row = ln * 4 + r;
      *(uint4*)(HsB + row * 256 + ((li * 16) ^ ((row & 7) << 4))) = p;
    }
  }
  __syncthreads();

  // ---------------- Phase 1: GEMM1 (swapped) ----------------
  const int wid = tid >> 6, lane = tid & 63;
  const int lg = lane >> 4, lr = lane & 15;
  const int swz = (lr & 7) << 4;

  f32x4 acc1[4][4] = {};   // [ht][rt]: D[hidden = wid*64+ht*16+lg*4+i][row = rt*16+lr]
#pragma unroll
  for (int ks = 0; ks < 4; ++ks) {
    short8 Bf[4];
#pragma unroll
    for (int rt = 0; rt < 4; ++rt)
      Bf[rt] = *(const short8*)(HsB + (rt * 16 + lr) * 256 + ((ks * 64 + lg * 16) ^ swz));
#pragma unroll
    for (int ht = 0; ht < 4; ++ht) {
      short8 Af = *(const short8*)(W1T + (size_t)(wid * 64 + ht * 16 + lr) * DF + ks * 32 + lg * 8);
#pragma unroll
      for (int rt = 0; rt < 4; ++rt)
        acc1[ht][rt] = __builtin_amdgcn_mfma_f32_16x16x32_bf16(Af, Bf[rt], acc1[ht][rt], 0, 0, 0);
    }
  }

  // bias + mish + packed As write (one b64 per (ht,rt))
#pragma unroll
  for (int ht = 0; ht < 4; ++ht) {
    const float4 bb = *(const float4*)&b1[wid * 64 + ht * 16 + lg * 4];
    const int chunk = wid * 128 + ht * 32 + (lg >> 1) * 16;
    const int sub = (lg & 1) * 8;
#pragma unroll
    for (int rt = 0; rt < 4; ++rt) {
      const int row = rt * 16 + lr;
      float m0 = mishf(acc1[ht][rt][0] + bb.x);
      float m1 = mishf(acc1[ht][rt][1] + bb.y);
      float m2 = mishf(acc1[ht][rt][2] + bb.z);
      float m3 = mishf(acc1[ht][rt][3] + bb.w);
      uint2 p; p.x = cvtpk(m0, m1); p.y = cvtpk(m2, m3);
      *(uint2*)(AsB + row * 512 + (chunk ^ ((row & 7) << 4)) + sub) = p;
    }
  }
  __syncthreads();

  // ---------------- Phase 2: GEMM2 ----------------
  f32x4 acc2[4][2] = {};   // [m][nr]: D[row = m*16+lg*4+reg][col = wid*32+nr*16+lr]
#pragma unroll
  for (int ks = 0; ks < 8; ++ks) {
    short8 Af[4];
#pragma unroll
    for (int m = 0; m < 4; ++m)
      Af[m] = *(const short8*)(AsB + (m * 16 + lr) * 512 + ((ks * 64 + lg * 16) ^ swz));
#pragma unroll
    for (int nr = 0; nr < 2; ++nr) {
      short8 Bf = *(const short8*)(W2T + (size_t)(wid * 32 + nr * 16 + lr) * HF + ks * 32 + lg * 8);
#pragma unroll
      for (int m = 0; m < 4; ++m)
        acc2[m][nr] = __builtin_amdgcn_mfma_f32_16x16x32_bf16(Af[m], Bf, acc2[m][nr], 0, 0, 0);
    }
  }

  // run-mean + bias + residual
  const int nodebase = blockIdx.x * 16;
#pragma unroll
  for (int m = 0; m < 4; ++m) {
    const int node = nodebase + m * 4 + lg;
#pragma unroll
    for (int nr = 0; nr < 2; ++nr) {
      const int col = wid * 32 + nr * 16 + lr;
      float mean = 0.25f * (acc2[m][nr][0] + acc2[m][nr][1] + acc2[m][nr][2] + acc2[m][nr][3]);
      out[(size_t)node * DF + col] = mean + b2[col] + x[(size_t)node * DF + col];
    }
  }
}

extern "C" void kernel_launch(void* const* d_in, const int* in_sizes, int n_in,
                              void* d_out, int out_size, void* d_ws, size_t ws_size,
                              hipStream_t stream) {
  const float* x             = (const float*)d_in[0];
  const int* ei              = (const int*)d_in[1];
  const unsigned char* dropb = (const unsigned char*)d_in[2];
  const int* dropi           = (const int*)d_in[2];
  const float* W1            = (const float*)d_in[3];
  const float* b1            = (const float*)d_in[4];
  const float* W2            = (const float*)d_in[5];
  const float* b2            = (const float*)d_in[6];
  float* out = (float*)d_out;

  unsigned short* wsh = (unsigned short*)d_ws;
  unsigned short* W1T = wsh + W1T_OFF;
  unsigned short* W2T = wsh + W2T_OFF;
  unsigned short* xbf = wsh + XBF_OFF;
  int* deg      = (int*)(wsh + INT_OFF);
  int* rowstart = deg + NN;
  int* cursor   = rowstart + NN;
  int* bsum     = cursor + NN;
  int* boff     = bsum + 256;
  unsigned* adj = (unsigned*)(boff + 256);
  int* flag     = (int*)(adj + NE);
  unsigned char* bits = (unsigned char*)(flag + 1);

  k_init<<<(NN * DF / 4) / 256, 256, 0, stream>>>(W1, W2, x, W1T, W2T, xbf, deg, flag);
  k_detect<<<(NR * NN + 255) / 256, 256, 0, stream>>>(dropb, flag);
  k_packhist<<<(NE + 255) / 256, 256, 0, stream>>>(dropb, dropi, flag, bits, ei, deg);
  k_scan1<<<NB1, 256, 0, stream>>>(deg, rowstart, bsum);
  k_scan2<<<1, 256, 0, stream>>>(bsum, boff);
  k_scan3<<<NB1, 256, 0, stream>>>(rowstart, boff, cursor);
  k_fill<<<(NE + 255) / 256, 256, 0, stream>>>(ei, bits, cursor, adj);
  k_mlp<<<NN / 16, 256, 0, stream>>>(x, xbf, adj, rowstart, deg, bits, W1T, W2T, b1, b2, out);
}